// Round 6
// baseline (62.712 us; speedup 1.0000x reference)
//
#include <hip/hip_runtime.h>
#include <hip/hip_bf16.h>

#define F_DIM 64
#define B_DIM 64
#define C_DIM 1024
#define BN 128        // o-tile width per pass
#define BK 64
#define NSTEP 32      // 2 passes x 16 K-steps
#define THREADS 512

using f32x4  = __attribute__((ext_vector_type(4))) float;
using bf16x8 = __attribute__((ext_vector_type(8))) short;
using s16x4  = __attribute__((ext_vector_type(4))) short;

// fp32 -> bf16 round-to-nearest-even
static __device__ __forceinline__ short f2bf(float f) {
    unsigned u = __float_as_uint(f);
    unsigned r = (u + 0x7fffu + ((u >> 16) & 1u)) >> 16;
    return (short)r;
}

__global__ __launch_bounds__(THREADS, 2)
void channelfc_kernel(const float* __restrict__ x,
                      const float* __restrict__ w,
                      const float* __restrict__ bias,
                      float* __restrict__ out)
{
    // R6 structure: X_f resident in LDS (copied ONCE per block), K-loop
    // streams only W. Kills the X L2-refetch that R2..R5 elimination left as
    // the only live theory (X re-requested 16x per block; W stream turns L2
    // over every ~4.6us, so X reuse depended on inter-block lockstep).
    // 256 blocks = 1/CU exactly; 4 blocks per feature, same XCD, request X_f
    // simultaneously at launch -> ~1 HBM fetch per feature.
    const int n    = blockIdx.x;       // 0..255
    const int xcd  = n & 7;            // dispatcher round-robins n -> XCD n%8
    const int loc  = n >> 3;           // 0..31 within XCD
    const int f    = xcd + 8 * (loc >> 2);
    const int bx   = loc & 3;          // which pair of o-tiles (o-tiles 2bx, 2bx+1)

    const int tid  = threadIdx.x;
    const int lane = tid & 63;
    const int wid  = tid >> 6;   // 0..7
    const int wr   = wid >> 2;   // 0..1 -> rows wr*32..+32
    const int wc   = wid & 3;    // 0..3 -> cols wc*32..+32

    // LDS = 128K (X) + 32K (W dbuf) = 163840 B = 160 KiB exactly (1 block/CU).
    // T2 XOR swizzle on both: (row, byte) at row*stride + (byte ^ ((row&7)<<4)).
    __shared__ short sX[B_DIM * C_DIM];   // X_f bf16, row=b, stride 2048 B
    __shared__ short sW[2][BN * BK];      // W tile bf16, row=o, stride 128 B

    const float* xA = x + (size_t)f * C_DIM;                 // + b*(F*C) + c
    const float* wB = w + (size_t)f * C_DIM * C_DIM;         // + o*C + c

    f32x4 rwA[4], rwB[4];   // W staging ping-pong (named sets, rule #20)

    auto loadW = [&](int s, f32x4 (&r)[4]) {
        const int o0 = (bx * 2 + (s >> 4)) * BN;
        const int k0 = (s & 15) * BK;
        #pragma unroll
        for (int i = 0; i < 4; ++i) {
            int id = i * THREADS + tid, row = id >> 4, k4 = id & 15;  // 16 float4/row
            r[i] = *(const f32x4*)(wB + (size_t)(o0 + row) * C_DIM + k0 + k4 * 4);
        }
    };
    auto storeW = [&](int buf, const f32x4 (&r)[4]) {
        #pragma unroll
        for (int i = 0; i < 4; ++i) {
            int id = i * THREADS + tid, row = id >> 4, k4 = id & 15;
            int byte = (k4 * 8) ^ ((row & 7) << 4);
            s16x4 v; v[0]=f2bf(r[i][0]); v[1]=f2bf(r[i][1]); v[2]=f2bf(r[i][2]); v[3]=f2bf(r[i][3]);
            *(s16x4*)((char*)&sW[buf][0] + row * 128 + byte) = v;
        }
    };

    // --- prologue: start W stream first, then copy X_f -> LDS (once) ---
    loadW(0, rwA);
    loadW(1, rwB);
    // X_f = 16384 f32x4 chunks / 512 thr = 32 per thread; unroll 8 at a time
    // to cap staging VGPRs (rule #20 / spill control).
    #pragma unroll 1
    for (int c8 = 0; c8 < 4; ++c8) {
        f32x4 tx[8];
        #pragma unroll
        for (int i = 0; i < 8; ++i) {
            int id = (c8 * 8 + i) * THREADS + tid;
            int row = id >> 8, k4 = id & 255;                 // 256 float4 per X row
            tx[i] = *(const f32x4*)(xA + (size_t)row * (F_DIM * C_DIM) + k4 * 4);
        }
        #pragma unroll
        for (int i = 0; i < 8; ++i) {
            int id = (c8 * 8 + i) * THREADS + tid;
            int row = id >> 8, k4 = id & 255;
            int byte = (k4 * 8) ^ ((row & 7) << 4);
            s16x4 v; v[0]=f2bf(tx[i][0]); v[1]=f2bf(tx[i][1]); v[2]=f2bf(tx[i][2]); v[3]=f2bf(tx[i][3]);
            *(s16x4*)((char*)&sX[0] + row * 2048 + byte) = v;
        }
    }
    storeW(0, rwA);
    __syncthreads();   // X + W(0) staged

    f32x4 acc[2][2] = {};   // wave sub-tile 32x32

    auto compute = [&](int buf, int s) {
        #pragma unroll
        for (int ks = 0; ks < 2; ++ks) {
            const int kx = (s & 15) * 128 + ks * 64 + (lane >> 4) * 16;  // byte in X row
            const int kw = ks * 64 + (lane >> 4) * 16;                   // byte in W row
            bf16x8 af[2], bfr[2];
            #pragma unroll
            for (int mt = 0; mt < 2; ++mt) {
                int row = wr * 32 + mt * 16 + (lane & 15);
                af[mt] = *(const bf16x8*)((const char*)&sX[0] + row * 2048 + (kx ^ ((row & 7) << 4)));
            }
            #pragma unroll
            for (int nt = 0; nt < 2; ++nt) {
                int row = wc * 32 + nt * 16 + (lane & 15);
                bfr[nt] = *(const bf16x8*)((const char*)&sW[buf][0] + row * 128 + (kw ^ ((row & 7) << 4)));
            }
            #pragma unroll
            for (int mt = 0; mt < 2; ++mt)
                #pragma unroll
                for (int nt = 0; nt < 2; ++nt)
                    acc[mt][nt] = __builtin_amdgcn_mfma_f32_16x16x32_bf16(af[mt], bfr[nt], acc[mt][nt], 0, 0, 0);
        }
    };

    // Epilogue: C/D layout (m89-verified): col = lane&15 (-> o), row = (lane>>4)*4 + reg (-> b)
    auto epilogue = [&](int p) {
        const int ocol0 = (bx * 2 + p) * BN;
        const int ncol_base = ocol0 + wc * 32 + (lane & 15);
        const int mrow_base = wr * 32 + (lane >> 4) * 4;
        #pragma unroll
        for (int nt = 0; nt < 2; ++nt) {
            const int o  = ncol_base + nt * 16;
            const float bv = bias[f * C_DIM + o];
            #pragma unroll
            for (int mt = 0; mt < 2; ++mt)
                #pragma unroll
                for (int r = 0; r < 4; ++r) {
                    const int b = mrow_base + mt * 16 + r;
                    out[((size_t)b * F_DIM + f) * C_DIM + o] = acc[mt][nt][r] + bv;
                }
        }
    };

    // Main loop, 2 steps/iter. Invariants at iter top: buf0 = W(s) staged,
    // rwB = W(s+1) in regs, barrier passed. Issue-before-wait ping-pong (at
    // 1 block/CU there is no sibling block to cover a drained HBM queue).
    // Race proof: storeW(1,..) writes buf1 while compute(0) reads buf0;
    // storeW(0,..) in the second half is after the mid barrier, which every
    // wave's compute(0) (buf0 reads) precedes; symmetric for buf1 at iter top.
    #pragma unroll 1
    for (int it = 0; it < 16; ++it) {
        const int s = 2 * it;
        if (s + 2 < NSTEP) loadW(s + 2, rwA);
        storeW(1, rwB);                     // stage W(s+1)
        compute(0, s);                      // consume W(s)
        __syncthreads();
        if (s + 3 < NSTEP) loadW(s + 3, rwB);
        if (s + 2 < NSTEP) storeW(0, rwA);  // stage W(s+2)
        compute(1, s + 1);                  // consume W(s+1)
        if (s + 1 == 15) {                  // pass-0 done: write its output
            epilogue(0);
            #pragma unroll
            for (int mt = 0; mt < 2; ++mt)
                #pragma unroll
                for (int nt = 0; nt < 2; ++nt)
                    acc[mt][nt] = f32x4{0.f, 0.f, 0.f, 0.f};
        }
        __syncthreads();
    }
    epilogue(1);
}

extern "C" void kernel_launch(void* const* d_in, const int* in_sizes, int n_in,
                              void* d_out, int out_size, void* d_ws, size_t ws_size,
                              hipStream_t stream) {
    const float* x    = (const float*)d_in[0];
    const float* w    = (const float*)d_in[1];
    const float* bias = (const float*)d_in[2];
    float* out        = (float*)d_out;
    // 256 blocks = 1 per CU (160 KiB LDS each); XCD-aware decode in-kernel.
    channelfc_kernel<<<dim3(256), dim3(THREADS), 0, stream>>>(x, w, bias, out);
}